// Round 8
// baseline (155.774 us; speedup 1.0000x reference)
//
#include <hip/hip_runtime.h>
#include <hip/hip_bf16.h>
#include <math.h>

#define B_ 4
#define S_ 4096
#define E_ 1024

typedef __attribute__((ext_vector_type(8))) short bf16x8;
typedef __attribute__((ext_vector_type(4))) short bf16x4;
typedef __attribute__((ext_vector_type(4))) float f32x4;

__device__ __forceinline__ unsigned short f2bf(float f) {
  unsigned u = __float_as_uint(f);
  u = u + 0x7fffu + ((u >> 16) & 1u);
  return (unsigned short)(u >> 16);
}

// ---------------- projection: Q/K/Vt = x @ W^T ----------------
// R1 body reindexed to 32-row blocks (grid 512 = 2 blocks/CU for latency
// overlap). Waves: rg=wave>>1 (16-row group), nh=wave&1 (96-col half).
// Staging maps / swizzles / epilogue verbatim R1 otherwise.
__global__ __launch_bounds__(256) void proj_kernel(
    const float* __restrict__ x, const float* __restrict__ Wq,
    const float* __restrict__ Wk, const float* __restrict__ Wv,
    unsigned short* __restrict__ Qp, unsigned short* __restrict__ Kb,
    unsigned short* __restrict__ Vt)
{
  __shared__ __align__(16) unsigned short xs[32*64];   // [32 m][64 k] bf16, swizzled
  __shared__ __align__(16) unsigned short wl[192*64];  // [192 n][64 k] bf16, swizzled
  const int tid = threadIdx.x;
  const int wave = tid >> 6, lane = tid & 63;
  const int l15 = lane & 15, l4 = lane >> 4;
  const int rg = wave >> 1, nh = wave & 1;
  const int m0 = blockIdx.x * 32;

  f32x4 acc[6];
  #pragma unroll
  for (int i = 0; i < 6; i++) acc[i] = (f32x4)0.f;

  f32x4 xr[2], wr[12];
  #pragma unroll
  for (int i = 0; i < 2; i++) {
    int c = tid + i*256; int row = c >> 4, cc = c & 15;
    xr[i] = *(const f32x4*)(x + (size_t)(m0 + row)*E_ + cc*4);
  }
  #pragma unroll
  for (int i = 0; i < 12; i++) {
    int c = tid + i*256; int n = c >> 4, cc = c & 15;
    const float* Wsrc = (n < 64) ? (Wq + (size_t)n*E_)
                     : ((n < 128) ? (Wk + (size_t)(n-64)*E_)
                                  : (Wv + (size_t)(n-128)*E_));
    wr[i] = *(const f32x4*)(Wsrc + cc*4);
  }

  for (int ks = 0; ks < 16; ks++) {
    __syncthreads();
    #pragma unroll
    for (int i = 0; i < 2; i++) {
      int c = tid + i*256; int row = c >> 4, cc = c & 15;
      bf16x4 v;
      v[0] = (short)f2bf(xr[i][0]); v[1] = (short)f2bf(xr[i][1]);
      v[2] = (short)f2bf(xr[i][2]); v[3] = (short)f2bf(xr[i][3]);
      *(bf16x4*)((char*)xs + row*128 + ((cc*8) ^ ((row&7)<<4))) = v;
    }
    #pragma unroll
    for (int i = 0; i < 12; i++) {
      int c = tid + i*256; int n = c >> 4, cc = c & 15;
      bf16x4 v;
      v[0] = (short)f2bf(wr[i][0]); v[1] = (short)f2bf(wr[i][1]);
      v[2] = (short)f2bf(wr[i][2]); v[3] = (short)f2bf(wr[i][3]);
      *(bf16x4*)((char*)wl + n*128 + ((cc*8) ^ ((n&7)<<4))) = v;
    }
    if (ks < 15) {
      #pragma unroll
      for (int i = 0; i < 2; i++) {
        int c = tid + i*256; int row = c >> 4, cc = c & 15;
        xr[i] = *(const f32x4*)(x + (size_t)(m0 + row)*E_ + (ks+1)*64 + cc*4);
      }
      #pragma unroll
      for (int i = 0; i < 12; i++) {
        int c = tid + i*256; int n = c >> 4, cc = c & 15;
        const float* Wsrc = (n < 64) ? (Wq + (size_t)n*E_)
                         : ((n < 128) ? (Wk + (size_t)(n-64)*E_)
                                      : (Wv + (size_t)(n-128)*E_));
        wr[i] = *(const f32x4*)(Wsrc + (ks+1)*64 + cc*4);
      }
    }
    __syncthreads();
    const int arow = rg*16 + l15;
    const int aswz = (arow&7)<<4;
    bf16x8 a0 = *(const bf16x8*)((const char*)xs + arow*128 + ((l4*16) ^ aswz));
    bf16x8 a1 = *(const bf16x8*)((const char*)xs + arow*128 + ((64 + l4*16) ^ aswz));
    #pragma unroll
    for (int j = 0; j < 6; j++) {
      int brow = (nh*6 + j)*16 + l15;
      int bswz = (brow&7)<<4;
      bf16x8 b0 = *(const bf16x8*)((const char*)wl + brow*128 + ((l4*16) ^ bswz));
      bf16x8 b1 = *(const bf16x8*)((const char*)wl + brow*128 + ((64 + l4*16) ^ bswz));
      acc[j] = __builtin_amdgcn_mfma_f32_16x16x32_bf16(a0, b0, acc[j], 0, 0, 0);
      acc[j] = __builtin_amdgcn_mfma_f32_16x16x32_bf16(a1, b1, acc[j], 0, 0, 0);
    }
  }

  const float QSC = 0.04508422f;  // log2(e) / sqrt(1024)
  const int mb = m0 + rg*16 + l4*4;
  const int b = m0 >> 12;
  const int sb = (m0 & 4095) + rg*16 + l4*4;
  #pragma unroll
  for (int j = 0; j < 6; j++) {
    int n = (nh*6 + j)*16 + l15;
    if (n < 64) {
      #pragma unroll
      for (int r = 0; r < 4; r++)
        Qp[(size_t)(mb + r)*64 + n] = f2bf(acc[j][r] * QSC);
    } else if (n < 128) {
      #pragma unroll
      for (int r = 0; r < 4; r++)
        Kb[(size_t)(mb + r)*64 + (n - 64)] = f2bf(acc[j][r]);
    } else {
      int d = n - 128;
      bf16x4 v;
      #pragma unroll
      for (int r = 0; r < 4; r++) v[r] = (short)f2bf(acc[j][r]);
      *(bf16x4*)(Vt + (size_t)(b*64 + d)*S_ + sb) = v;
    }
  }
}

// ---------------- causal flash attention, QBLK=64 + split-K ----------------
// (verbatim round-7 — proven correct)
__global__ __launch_bounds__(256) void attn_kernel(
    const unsigned short* __restrict__ Qp,
    const unsigned short* __restrict__ Kb,
    const unsigned short* __restrict__ Vt,
    float* __restrict__ out,
    float* __restrict__ Opart, float* __restrict__ spart, int NS)
{
  __shared__ __align__(16) unsigned short Ks[64*64];  // [64 k][64 d], swizzled
  __shared__ __align__(16) unsigned short Vs[64*64];  // [64 d][64 k], swizzled

  const int tid = threadIdx.x;
  const int wave = tid >> 6, lane = tid & 63;
  const int l15 = lane & 15, l4 = lane >> 4;
  const int g = wave;

  const int bid = blockIdx.x;               // grid = 4 * 32 * NS
  const int lg = (NS == 4) ? 2 : ((NS == 2) ? 1 : 0);
  const int b  = bid & 3;
  const int ks = (bid >> 2) & (NS - 1);
  const int p  = bid >> (2 + lg);           // 0..31

  const unsigned short* Qb  = Qp + (size_t)b*S_*64;
  const unsigned short* Kbb = Kb + (size_t)b*S_*64;
  const unsigned short* Vtb = Vt + (size_t)b*64*S_;
  float* outb = out + (size_t)b*S_*64;

  #pragma unroll 1
  for (int half = 0; half < 2; half++) {
    const int jq = half ? (63 - p) : p;
    const int q0 = jq * 64;
    const int ntile = jq + 1;
    const int tb = ntile / NS, tr = ntile % NS;
    const int kbeg = ks*tb + (ks < tr ? ks : tr);
    const int kend = kbeg + tb + (ks < tr ? 1 : 0);
    const int qrow = q0 + g*16 + l15;

    bf16x8 qf0 = *(const bf16x8*)(Qb + (size_t)qrow*64 + l4*8);
    bf16x8 qf1 = *(const bf16x8*)(Qb + (size_t)qrow*64 + 32 + l4*8);

    float m = -INFINITY, lsum = 0.f;
    f32x4 acc[4];
    #pragma unroll
    for (int i = 0; i < 4; i++) acc[i] = (f32x4)0.f;

    f32x4 kreg[2], vreg[2];
    if (kbeg < kend) {
      #pragma unroll
      for (int i = 0; i < 2; i++) {
        int c = tid + i*256; int row = c >> 3, cc = c & 7;
        kreg[i] = *(const f32x4*)((const char*)Kbb + (size_t)(kbeg*64 + row)*128 + cc*16);
        vreg[i] = *(const f32x4*)((const char*)Vtb + (size_t)row*8192 + (size_t)kbeg*128 + cc*16);
      }
    }

    for (int t = kbeg; t < kend; t++) {
      __syncthreads();
      #pragma unroll
      for (int i = 0; i < 2; i++) {
        int c = tid + i*256; int row = c >> 3, cc = c & 7;
        *(f32x4*)((char*)Ks + row*128 + ((cc*16) ^ ((row&7)<<4))) = kreg[i];
        *(f32x4*)((char*)Vs + row*128 + ((cc*16) ^ ((row&7)<<4))) = vreg[i];
      }
      if (t + 1 < kend) {
        #pragma unroll
        for (int i = 0; i < 2; i++) {
          int c = tid + i*256; int row = c >> 3, cc = c & 7;
          kreg[i] = *(const f32x4*)((const char*)Kbb + (size_t)((t+1)*64 + row)*128 + cc*16);
          vreg[i] = *(const f32x4*)((const char*)Vtb + (size_t)row*8192 + (size_t)(t+1)*128 + cc*16);
        }
      }
      __syncthreads();

      f32x4 sv[4];
      #pragma unroll
      for (int kt = 0; kt < 4; kt++) {
        int krow = kt*16 + l15;
        const char* kbp = (const char*)Ks + krow*128;
        int swz = (krow&7)<<4;
        bf16x8 k0f = *(const bf16x8*)(kbp + ((l4*16) ^ swz));
        bf16x8 k1f = *(const bf16x8*)(kbp + ((64 + l4*16) ^ swz));
        f32x4 z = (f32x4)0.f;
        z = __builtin_amdgcn_mfma_f32_16x16x32_bf16(k0f, qf0, z, 0, 0, 0);
        z = __builtin_amdgcn_mfma_f32_16x16x32_bf16(k1f, qf1, z, 0, 0, 0);
        sv[kt] = z;
      }
      if (t == ntile - 1) {
        #pragma unroll
        for (int kt = 0; kt < 4; kt++) {
          #pragma unroll
          for (int r = 0; r < 4; r++) {
            int kg = t*64 + kt*16 + l4*4 + r;
            if (kg > qrow) sv[kt][r] = -INFINITY;
          }
        }
      }
      float pmax = sv[0][0];
      #pragma unroll
      for (int kt = 0; kt < 4; kt++) {
        #pragma unroll
        for (int r = 0; r < 4; r++) pmax = fmaxf(pmax, sv[kt][r]);
      }
      pmax = fmaxf(pmax, __shfl_xor(pmax, 16, 64));
      pmax = fmaxf(pmax, __shfl_xor(pmax, 32, 64));
      float mnew = fmaxf(m, pmax);
      float msafe = (mnew == -INFINITY) ? 0.f : mnew;
      float scale = exp2f(m - msafe);
      float pv[16]; float psum = 0.f;
      #pragma unroll
      for (int i = 0; i < 16; i++) {
        pv[i] = exp2f(sv[i>>2][i&3] - msafe);
        psum += pv[i];
      }
      psum += __shfl_xor(psum, 16, 64);
      psum += __shfl_xor(psum, 32, 64);
      lsum = lsum*scale + psum;
      m = mnew;
      #pragma unroll
      for (int i = 0; i < 4; i++) acc[i] *= scale;
      bf16x8 pf0, pf1;
      #pragma unroll
      for (int i = 0; i < 8; i++) { pf0[i] = (short)f2bf(pv[i]); pf1[i] = (short)f2bf(pv[8+i]); }
      #pragma unroll
      for (int dt = 0; dt < 4; dt++) {
        int drow = dt*16 + l15;
        const char* vb = (const char*)Vs + drow*128;
        int swz = (drow&7)<<4;
        bf16x4 a0 = *(const bf16x4*)(vb + ((l4*8) ^ swz));
        bf16x4 a1 = *(const bf16x4*)(vb + ((32 + l4*8) ^ swz));
        bf16x4 a2 = *(const bf16x4*)(vb + ((64 + l4*8) ^ swz));
        bf16x4 a3 = *(const bf16x4*)(vb + ((96 + l4*8) ^ swz));
        bf16x8 vf0, vf1;
        #pragma unroll
        for (int i = 0; i < 4; i++) {
          vf0[i] = a0[i]; vf0[i+4] = a1[i];
          vf1[i] = a2[i]; vf1[i+4] = a3[i];
        }
        acc[dt] = __builtin_amdgcn_mfma_f32_16x16x32_bf16(vf0, pf0, acc[dt], 0, 0, 0);
        acc[dt] = __builtin_amdgcn_mfma_f32_16x16x32_bf16(vf1, pf1, acc[dt], 0, 0, 0);
      }
    } // KV tiles

    if (NS == 1) {
      float inv = 1.f / lsum;
      #pragma unroll
      for (int dt = 0; dt < 4; dt++)
        *(f32x4*)(outb + (size_t)qrow*64 + dt*16 + l4*4) = acc[dt] * inv;
    } else {
      int slot = (b*64 + jq)*NS + ks;
      float* Ob = Opart + (size_t)slot*4096 + (g*16 + l15)*64;
      #pragma unroll
      for (int dt = 0; dt < 4; dt++)
        *(f32x4*)(Ob + dt*16 + l4*4) = acc[dt];
      if (l4 == 0) {
        spart[(size_t)slot*128 + (g*16 + l15)*2]     = m;
        spart[(size_t)slot*128 + (g*16 + l15)*2 + 1] = lsum;
      }
    }
  } // half
}

// ---------------- cross-split merge ----------------
__global__ __launch_bounds__(256) void merge_kernel(
    const float* __restrict__ Opart, const float* __restrict__ spart,
    float* __restrict__ out, int NS)
{
  const int bid = blockIdx.x;          // 256 = 4 batches x 64 jq
  const int b = bid & 3, jq = bid >> 2;
  const int q = threadIdx.x >> 2;      // 0..63
  const int dq = threadIdx.x & 3;      // 16-float chunk
  const int base = (b*64 + jq) * NS;

  float M = -INFINITY;
  for (int i = 0; i < NS; i++)
    M = fmaxf(M, spart[(size_t)(base+i)*128 + q*2]);
  float wsum = 0.f;
  f32x4 o0 = (f32x4)0.f, o1 = (f32x4)0.f, o2 = (f32x4)0.f, o3 = (f32x4)0.f;
  for (int i = 0; i < NS; i++) {
    float mi = spart[(size_t)(base+i)*128 + q*2];
    float li = spart[(size_t)(base+i)*128 + q*2 + 1];
    float a = exp2f(mi - M);
    wsum += li * a;
    const float* op = Opart + (size_t)(base+i)*4096 + q*64 + dq*16;
    o0 += a * (*(const f32x4*)op);
    o1 += a * (*(const f32x4*)(op + 4));
    o2 += a * (*(const f32x4*)(op + 8));
    o3 += a * (*(const f32x4*)(op + 12));
  }
  float inv = 1.f / wsum;
  float* dst = out + (size_t)b*S_*64 + (size_t)(jq*64 + q)*64 + dq*16;
  *(f32x4*)dst       = o0 * inv;
  *(f32x4*)(dst + 4) = o1 * inv;
  *(f32x4*)(dst + 8) = o2 * inv;
  *(f32x4*)(dst + 12)= o3 * inv;
}

extern "C" void kernel_launch(void* const* d_in, const int* in_sizes, int n_in,
                              void* d_out, int out_size, void* d_ws, size_t ws_size,
                              hipStream_t stream)
{
  const float* x  = (const float*)d_in[0];
  const float* Wq = (const float*)d_in[1];
  const float* Wk = (const float*)d_in[2];
  const float* Wv = (const float*)d_in[3];
  unsigned short* Qp  = (unsigned short*)d_ws;                 // 2 MB
  unsigned short* Kbp = Qp  + (size_t)B_*S_*64;                // 2 MB
  unsigned short* Vtp = Kbp + (size_t)B_*S_*64;                // 2 MB
  float* out = (float*)d_out;

  const size_t qkv = (size_t)B_*S_*64*2*3;                     // 6,291,456 B
  const size_t per_ns = (size_t)256*4096*4 + (size_t)256*128*4;
  int NS = (ws_size >= qkv + 4*per_ns) ? 4
         : (ws_size >= qkv + 2*per_ns) ? 2 : 1;
  float* Opart = (float*)((char*)d_ws + qkv);
  float* spart = (float*)((char*)d_ws + qkv + (size_t)NS*256*4096*4);

  hipLaunchKernelGGL(proj_kernel, dim3(512), dim3(256), 0, stream,
                     x, Wq, Wk, Wv, Qp, Kbp, Vtp);
  hipLaunchKernelGGL(attn_kernel, dim3(4*32*NS), dim3(256), 0, stream,
                     Qp, Kbp, Vtp, out, Opart, spart, NS);
  if (NS > 1)
    hipLaunchKernelGGL(merge_kernel, dim3(256), dim3(256), 0, stream,
                       Opart, spart, out, NS);
}